// Round 1
// baseline (30.012 us; speedup 1.0000x reference)
//
#include <hip/hip_runtime.h>

// CropRoi: 3D adaptive max-pool over per-proposal crop boxes.
// f:        [B=4, C=64, 24, 24, 24] f32
// proposals:[N, 8] f32 = [b, score, cx, cy, cz, sx, sy, sz]
// out:      [N, C, 7, 7, 7] f32
//
// Semantics (must match jnp reference exactly):
//   c0f = center - side/2 ; c1f = c0f + side         (f32 math)
//   c0  = max(floor(c0f/scale), 0)                   (f32 div, floorf)
//   c1  = min(ceil (c1f/scale), 24)
//   Lc  = c1 - c0
//   bin i along an axis covers [c0 + i*Lc//S, c0 + ((i+1)*Lc + S-1)//S)
//   (integer floor division; bins are provably non-empty for this input range)

#define SS 7          // rcnn_crop_size
#define CC 64         // channels
#define DP 24         // pooled spatial extent (96/4)
#define INV_SCALE 0.25f

__global__ __launch_bounds__(256) void croproi_kernel(
    const float* __restrict__ f,       // [B, C, DP, DP, DP]
    const float* __restrict__ props,   // [N, 8]
    float* __restrict__ out,           // [N, C, SS, SS, SS]
    int total)
{
    int tid = blockIdx.x * blockDim.x + threadIdx.x;
    if (tid >= total) return;

    // decode: tid = (((n*CC + c)*SS + i)*SS + j)*SS + k
    int k = tid % SS;
    int t = tid / SS;
    int j = t % SS; t /= SS;
    int i = t % SS; t /= SS;
    int c = t % CC;
    int n = t / CC;

    const float* p = props + n * 8;
    int b = (int)p[0];

    int lo0, lo1, lo2, L0, L1, L2;
    {
        // axis 0 (z / D)
        float c0f = p[2] - 0.5f * p[5];
        float c1f = c0f + p[5];
        int lo = (int)floorf(c0f * INV_SCALE); if (lo < 0) lo = 0;
        int hi = (int)ceilf (c1f * INV_SCALE); if (hi > DP) hi = DP;
        lo0 = lo; L0 = hi - lo;
        // axis 1 (y / H)
        c0f = p[3] - 0.5f * p[6];
        c1f = c0f + p[6];
        lo = (int)floorf(c0f * INV_SCALE); if (lo < 0) lo = 0;
        hi = (int)ceilf (c1f * INV_SCALE); if (hi > DP) hi = DP;
        lo1 = lo; L1 = hi - lo;
        // axis 2 (x / W)
        c0f = p[4] - 0.5f * p[7];
        c1f = c0f + p[7];
        lo = (int)floorf(c0f * INV_SCALE); if (lo < 0) lo = 0;
        hi = (int)ceilf (c1f * INV_SCALE); if (hi > DP) hi = DP;
        lo2 = lo; L2 = hi - lo;
    }

    int zs = lo0 + (i * L0) / SS;
    int ze = lo0 + ((i + 1) * L0 + SS - 1) / SS;
    int ys = lo1 + (j * L1) / SS;
    int ye = lo1 + ((j + 1) * L1 + SS - 1) / SS;
    int xs = lo2 + (k * L2) / SS;
    int xe = lo2 + ((k + 1) * L2 + SS - 1) / SS;

    const float* fb = f + (size_t)(b * CC + c) * (DP * DP * DP);

    float m = -INFINITY;
    for (int z = zs; z < ze; ++z) {
        for (int y = ys; y < ye; ++y) {
            const float* row = fb + (z * DP + y) * DP;
            for (int x = xs; x < xe; ++x) {
                m = fmaxf(m, row[x]);
            }
        }
    }
    out[tid] = m;
}

extern "C" void kernel_launch(void* const* d_in, const int* in_sizes, int n_in,
                              void* d_out, int out_size, void* d_ws, size_t ws_size,
                              hipStream_t stream) {
    const float* f     = (const float*)d_in[0];
    const float* props = (const float*)d_in[2];
    float* out = (float*)d_out;

    int N = in_sizes[2] / 8;                 // 96
    int total = N * CC * SS * SS * SS;       // == out_size

    int block = 256;
    int grid = (total + block - 1) / block;
    croproi_kernel<<<grid, block, 0, stream>>>(f, props, out, total);
}